// Round 3
// baseline (27706.506 us; speedup 1.0000x reference)
//
#include <hip/hip_runtime.h>
#include <hip/hip_fp16.h>

#define NTRAJ   256
#define NTP     512
#define NSTEPS  511
#define LATENT  256
#define INPUT   128
#define DEC_OUT 128

#define OUT_VOL ((size_t)NTRAJ * LATENT)                              // 65536
#define OUT_DTS (OUT_VOL + (size_t)NTRAJ * NSTEPS * DEC_OUT)          // 16809984

// Pair-interleaved fp16 weight workspace (offsets in uint32 = half2 units).
// Layout per matrix [K][C]: ws[kp*C + c] = half2(W[2kp][c], W[2kp+1][c]).
#define WU_UG1  0
#define WU_UG2  49152
#define WU_UGT1 81920
#define WU_UGT2 131072
#define WU_RG1  163840
#define WU_RG2  212992
#define WU_NS1  245760
#define WU_NS2  294912
#define WU_DK1  327680
#define WU_DEC  360448
#define WU_TOT  376832

typedef _Float16 h2_t __attribute__((ext_vector_type(2)));
union U32H2 { unsigned int u; h2_t h; };

__device__ __forceinline__ float dot2f(unsigned int wu, unsigned int xu, float acc) {
#if defined(__has_builtin) && __has_builtin(__builtin_amdgcn_fdot2)
    U32H2 a, b; a.u = wu; b.u = xu;
    return __builtin_amdgcn_fdot2(a.h, b.h, acc, false);
#else
    U32H2 a, b; a.u = wu; b.u = xu;
    return acc + (float)a.h.x * (float)b.h.x + (float)a.h.y * (float)b.h.y;
#endif
}

__device__ __forceinline__ float wred(float v) {
    #pragma unroll
    for (int off = 32; off; off >>= 1) v += __shfl_down(v, off, 64);
    return v;
}
__device__ __forceinline__ float fast_sigmoid(float x) { return 1.0f / (1.0f + __expf(-x)); }
__device__ __forceinline__ float fast_tanh(float x) {
    float e = __expf(2.0f * x);
    return 1.0f - 2.0f / (e + 1.0f);
}
// Pack (v_even, v_odd) from adjacent lanes into one half2; only even lanes
// hold the correct result and write. Must be called by full waves.
__device__ __forceinline__ unsigned int packpair(float v) {
    float vn = __shfl_xor(v, 1, 64);
    U32H2 r; r.h.x = (_Float16)v; r.h.y = (_Float16)vn;
    return r.u;
}

// Raw barrier: LDS ordering only — global (weight) loads stay in flight
// across it. __syncthreads would drain vmcnt(0) and kill cross-stage
// weight prefetch.
__device__ __forceinline__ void barx() {
    asm volatile("s_waitcnt lgkmcnt(0)");
    __builtin_amdgcn_s_barrier();
    __builtin_amdgcn_sched_barrier(0);
}

// ---- weight prep: fp32 -> k-pair-interleaved half2 ----
extern "C" __global__ void __launch_bounds__(256)
convert_w(const float* __restrict__ ug_w1, const float* __restrict__ ug_w2,
          const float* __restrict__ ugt_w1, const float* __restrict__ ugt_w2,
          const float* __restrict__ rg_w1, const float* __restrict__ rg_w2,
          const float* __restrict__ ns_w1, const float* __restrict__ ns_w2,
          const float* __restrict__ dk_w1, const float* __restrict__ dec_w,
          unsigned int* __restrict__ ws)
{
    const int i = blockIdx.x * 256 + threadIdx.x;
    const float* s; int o; int cbits;
    if      (i < WU_UG2)  { s = ug_w1;  o = i;           cbits = 8; }
    else if (i < WU_UGT1) { s = ug_w2;  o = i - WU_UG2;  cbits = 8; }
    else if (i < WU_UGT2) { s = ugt_w1; o = i - WU_UGT1; cbits = 8; }
    else if (i < WU_RG1)  { s = ugt_w2; o = i - WU_UGT2; cbits = 8; }
    else if (i < WU_RG2)  { s = rg_w1;  o = i - WU_RG1;  cbits = 8; }
    else if (i < WU_NS1)  { s = rg_w2;  o = i - WU_RG2;  cbits = 8; }
    else if (i < WU_NS2)  { s = ns_w1;  o = i - WU_NS1;  cbits = 8; }
    else if (i < WU_DK1)  { s = ns_w2;  o = i - WU_NS2;  cbits = 8; }
    else if (i < WU_DEC)  { s = dk_w1;  o = i - WU_DK1;  cbits = 8; }
    else                  { s = dec_w;  o = i - WU_DEC;  cbits = 7; }
    const int C  = 1 << cbits;
    const int kp = o >> cbits;
    const int c  = o & (C - 1);
    const float v0 = s[(2 * kp) * C + c];
    const float v1 = s[(2 * kp + 1) * C + c];
    const unsigned int h0 = __half_as_ushort(__float2half(v0));
    const unsigned int h1 = __half_as_ushort(__float2half(v1));
    ws[i] = h0 | (h1 << 16);
}

// Macro hygiene: no parameter named x/y/z/w (body does member access).
#define DOT1(acc, wv, xv) { \
    acc.x = dot2f((wv).x, (xv), acc.x); acc.y = dot2f((wv).y, (xv), acc.y); \
    acc.z = dot2f((wv).z, (xv), acc.z); acc.w = dot2f((wv).w, (xv), acc.w); }

// Dot a 4-kp weight chunk (uint4 Wb[4]) against 4 half2 x values packed in
// one uint4 (component j pairs with Wb[j]).
#define DOT4(acc, Wb, xq) { \
    DOT1(acc, Wb[0], (xq).x); DOT1(acc, Wb[1], (xq).y); \
    DOT1(acc, Wb[2], (xq).z); DOT1(acc, Wb[3], (xq).w); }

// Load a 4-kp weight chunk (col-stride 256) for chunk index ch.
#define LDW4(dst, P, kpb, ch) { \
    _Pragma("unroll") \
    for (int j_ = 0; j_ < 4; ++j_) \
        dst[j_] = *(const uint4*)((P) + (size_t)((kpb) + (ch) * 4 + j_) * 256 + cl4); }

extern "C" __global__ void __launch_bounds__(512, 2)
rnn_decay_kernel3(const float* __restrict__ data, const float* __restrict__ ts,
                  const float* __restrict__ ug_b1, const float* __restrict__ ug_b2,
                  const float* __restrict__ ugt_b1, const float* __restrict__ ugt_b2,
                  const float* __restrict__ rg_b1, const float* __restrict__ rg_b2,
                  const float* __restrict__ ns_b1, const float* __restrict__ ns_b2,
                  const float* __restrict__ dk_b1, const float* __restrict__ dk_w2,
                  const float* __restrict__ dk_b2, const float* __restrict__ dec_b,
                  const unsigned int* __restrict__ wsu, float* __restrict__ out)
{
    __shared__ __align__(16) float s_part[8192];        // GEMV partials (reused)
    __shared__ __align__(16) unsigned int s_in_h[192];  // [ydec(128)|xh(64)] half2
    __shared__ __align__(16) unsigned int s_ns_h[192];  // [y*r (128)|xh(64)] half2
    __shared__ __align__(16) unsigned int s_y_h[128];   // y half2 (dk1 src)
    __shared__ __align__(16) unsigned int s_a_h[128];   // gate-h / ns-h half2
    __shared__ __align__(16) unsigned int s_b_h[128];
    __shared__ __align__(16) unsigned int s_c_h[128];
    __shared__ __align__(16) unsigned int s_v_h[128];   // vol half2
    __shared__ float s_ut[256];
    __shared__ float s_red[8];                          // [0..3] mask, [4..7] dk

    const int tid  = threadIdx.x;
    const int w    = tid >> 6;
    const int lane = tid & 63;
    const int c    = tid & 255;
    const int cl4  = lane << 2;                          // 4 uint cols per lane
    const int traj = blockIdx.x;

    const unsigned int* UG1  = wsu + WU_UG1;  const unsigned int* UG2  = wsu + WU_UG2;
    const unsigned int* UGT1 = wsu + WU_UGT1; const unsigned int* UGT2 = wsu + WU_UGT2;
    const unsigned int* RG1  = wsu + WU_RG1;  const unsigned int* RG2  = wsu + WU_RG2;
    const unsigned int* NS1  = wsu + WU_NS1;  const unsigned int* NS2  = wsu + WU_NS2;
    const unsigned int* DK1  = wsu + WU_DK1;  const unsigned int* DECW = wsu + WU_DEC;

    const float* dbase = data + (size_t)traj * NTP * (2 * INPUT);
    const float* tbase = ts + (size_t)traj * NTP;
    float* vol_out = out + OUT_VOL + (size_t)traj * NSTEPS * DEC_OUT;
    float* dts_out = out + OUT_DTS + (size_t)traj * NSTEPS;

    if (tid < 256)
        for (int t0 = c; t0 < NSTEPS; t0 += 256)
            dts_out[t0] = tbase[t0 + 1] - tbase[t0];

    // Hoisted per-thread constants (weight stream thrashes L1; these were
    // L2-miss latency on the serial reduce critical paths).
    const float b1sel = ((tid >> 8) ? ugt_b1 : ug_b1)[c];
    const float b2sel = ((tid >> 8) ? ugt_b2 : ug_b2)[c];
    const float rgb1  = rg_b1[c];
    const float rgb2  = rg_b2[c];
    const float nsb1  = ns_b1[c];
    const float nsb2  = ns_b2[c];
    const float dkb1  = dk_b1[c];
    const float dkw2  = dk_w2[c];
    const float dkb2  = dk_b2[0];
    const float decb  = dec_b[tid & 127];

    float r_y = 0.f, r_yt = 0.f;

    const int kp24 = w * 24;
    const int kp16 = w << 4;

    // Cross-barrier prefetch buffers: each exactly 4×uint4 = 16 VGPRs, with
    // non-overlapping live ranges (round-1 lesson: larger arrays spill →
    // scratch thrash → 40 GB HBM refetch).
    uint4 pfDK[4];            // DK1 chunk0; set in ns2 phase, used next iter

    for (int t = -1; t < NSTEPS; ++t) {
        const bool first = (t < 0);

        // ---- stage x, mask partials, xh pack; fetch dt early ----
        float dt_t = 0.f;
        if (tid < 256) {
            const float xval = first ? dbase[c] : dbase[(size_t)(t + 1) * 256 + c];
            if (!first) dt_t = tbase[t + 1] - tbase[t];
            float mv = (c >= 128) ? xval : 0.f;
            mv = wred(mv);
            if (lane == 0) s_red[w] = mv;               // w in 0..3 here
            if (c < 128) {
                const unsigned int px = packpair(xval);
                if (!(lane & 1)) { s_in_h[128 + (c >> 1)] = px; s_ns_h[128 + (c >> 1)] = px; }
            }
            if (first && !(lane & 1)) s_in_h[c >> 1] = 0u;   // ydec = 0
        }

        float r_ydec = 0.f, r_u = 0.f, r_r = 0.f;
        bool maskv;

        uint4 pfG1[4], pfG2[4], pfNS1[4], pfNS2[4];

        if (!first) {
            // ---- dk1: y @ dk_w1, K=256 (4 chunks; chunk0 prefetched last iter) ----
            const uint4* sy = (const uint4*)(s_y_h + kp16);
            float4 aD = make_float4(0.f, 0.f, 0.f, 0.f);
            {
                uint4 dA[4], dB[4];
                const uint4 xq0 = sy[0];
                LDW4(dA, DK1, kp16, 1);  const uint4 xq1 = sy[1];
                DOT4(aD, pfDK, xq0);
                LDW4(dB, DK1, kp16, 2);  const uint4 xq2 = sy[2];
                DOT4(aD, dA, xq1);
                LDW4(dA, DK1, kp16, 3);  const uint4 xq3 = sy[3];
                DOT4(aD, dB, xq2);
                LDW4(pfG1, UG1, kp24, 0);        // covers B1..B3 region
                DOT4(aD, dA, xq3);
            }
            *(float4*)(s_part + (w << 8) + cl4) = aD;
            barx();                                            // B1
            if (tid < 256) {
                float v = dkb1;
                #pragma unroll
                for (int i = 0; i < 8; ++i) v += s_part[(i << 8) + c];
                v = fmaxf(v, 0.f);
                const float pv = wred(v * dkw2);
                if (lane == 0) s_red[4 + w] = pv;
            }
            barx();                                            // B2
            const float decay = fmaxf(s_red[4] + s_red[5] + s_red[6] + s_red[7] + dkb2, 0.f);
            maskv = (s_red[0] + s_red[1] + s_red[2] + s_red[3]) > 0.f;
            if (tid < 256) {
                const float diff = r_y - r_yt;
                const float ef = __expf(-decay * dt_t);
                const float eh = __expf(-0.5f * decay * dt_t);
                r_ydec = r_yt + diff * ef;
                const float vol = 0.5f * (r_y + r_yt + diff * eh);
                const unsigned int pd  = packpair(r_ydec);
                const unsigned int pvv = packpair(vol);
                if (!(lane & 1)) { s_in_h[c >> 1] = pd; s_v_h[c >> 1] = pvv; }
            }
            barx();                                            // B3
        } else {
            LDW4(pfG1, UG1, kp24, 0);
            barx();                                            // B3
            maskv = (s_red[0] + s_red[1] + s_red[2] + s_red[3]) > 0.f;
        }

        // ---- dec (K=256, src s_v_h) ----
        if (!first) {
            float4 aE = make_float4(0.f, 0.f, 0.f, 0.f);
            const int hh = lane >> 5, cl = (lane & 31) << 2;
            const int kpb = kp16 + hh;
            #pragma unroll 4
            for (int i = 0; i < 8; ++i) {
                const int kp = kpb + (i << 1);
                const uint4 wv = *(const uint4*)(DECW + (size_t)kp * 128 + cl);
                const unsigned int xv_ = s_v_h[kp];
                DOT1(aE, wv, xv_);
            }
            *(float4*)(s_part + 6144 + ((w << 1) + hh) * 128 + cl) = aE;
        }

        // ---- group1: ug1/ugt1/rg1 (K=384, 6 chunks, src s_in_h) ----
        {
            const uint4* sx = (const uint4*)(s_in_h + kp24);
            float4 aA = make_float4(0.f,0.f,0.f,0.f), aB = aA, aC = aA;
            uint4 ga[4], gb[4], gc[4], ha[4], hb[4], hc[4];
            const uint4 xq0 = sx[0];
            LDW4(gb, UGT1, kp24, 0); LDW4(gc, RG1, kp24, 0);
            LDW4(ha, UG1, kp24, 1); LDW4(hb, UGT1, kp24, 1); LDW4(hc, RG1, kp24, 1);
            const uint4 xq1 = sx[1];
            DOT4(aA, pfG1, xq0); DOT4(aB, gb, xq0); DOT4(aC, gc, xq0);
            LDW4(ga, UG1, kp24, 2); LDW4(gb, UGT1, kp24, 2); LDW4(gc, RG1, kp24, 2);
            const uint4 xq2 = sx[2];
            DOT4(aA, ha, xq1); DOT4(aB, hb, xq1); DOT4(aC, hc, xq1);
            LDW4(ha, UG1, kp24, 3); LDW4(hb, UGT1, kp24, 3); LDW4(hc, RG1, kp24, 3);
            const uint4 xq3 = sx[3];
            DOT4(aA, ga, xq2); DOT4(aB, gb, xq2); DOT4(aC, gc, xq2);
            LDW4(ga, UG1, kp24, 4); LDW4(gb, UGT1, kp24, 4); LDW4(gc, RG1, kp24, 4);
            const uint4 xq4 = sx[4];
            DOT4(aA, ha, xq3); DOT4(aB, hb, xq3); DOT4(aC, hc, xq3);
            LDW4(ha, UG1, kp24, 5); LDW4(hb, UGT1, kp24, 5); LDW4(hc, RG1, kp24, 5);
            const uint4 xq5 = sx[5];
            DOT4(aA, ga, xq4); DOT4(aB, gb, xq4); DOT4(aC, gc, xq4);
            LDW4(pfG2, UG2, kp16, 0);            // covers B4..B5 region
            DOT4(aA, ha, xq5); DOT4(aB, hb, xq5); DOT4(aC, hc, xq5);
            *(float4*)(s_part + (w << 8) + cl4)          = aA;
            *(float4*)(s_part + 2048 + (w << 8) + cl4)   = aB;
            *(float4*)(s_part + 4096 + (w << 8) + cl4)   = aC;
        }
        barx();                                                // B4
        {   // reduce + tanh + pack to half2 srcs
            const int s = tid >> 8;
            float v = b1sel;
            const float* pb = s_part + (s ? 2048 : 0) + c;
            #pragma unroll
            for (int i = 0; i < 8; ++i) v += pb[i << 8];
            v = fast_tanh(v);
            const unsigned int pk = packpair(v);
            if (!(lane & 1)) (s ? s_b_h : s_a_h)[c >> 1] = pk;
            if (tid < 256) {
                float v2 = rgb1;
                const float* pb2 = s_part + 4096 + c;
                #pragma unroll
                for (int i = 0; i < 8; ++i) v2 += pb2[i << 8];
                v2 = fast_tanh(v2);
                const unsigned int pk2 = packpair(v2);
                if (!(lane & 1)) s_c_h[c >> 1] = pk2;
            }
            if (!first && tid < 128) {
                float vd = decb;
                const float* pbd = s_part + 6144 + tid;
                #pragma unroll
                for (int i = 0; i < 16; ++i) vd += pbd[i << 7];
                vol_out[(size_t)t * DEC_OUT + tid] = vd;
            }
        }
        barx();                                                // B5

        // ---- group2: ug2/ugt2/rg2 (K=256, 4 chunks; srcs s_a_h/s_b_h/s_c_h) ----
        {
            const uint4* pa_ = (const uint4*)(s_a_h + kp16);
            const uint4* pb_ = (const uint4*)(s_b_h + kp16);
            const uint4* pc_ = (const uint4*)(s_c_h + kp16);
            float4 aA = make_float4(0.f,0.f,0.f,0.f), aB = aA, aC = aA;
            uint4 ga[4], gb[4], gc[4], ha[4], hb[4], hc[4];
            const uint4 xa0 = pa_[0], xb0 = pb_[0], xc0 = pc_[0];
            LDW4(gb, UGT2, kp16, 0); LDW4(gc, RG2, kp16, 0);
            LDW4(ha, UG2, kp16, 1); LDW4(hb, UGT2, kp16, 1); LDW4(hc, RG2, kp16, 1);
            const uint4 xa1 = pa_[1], xb1 = pb_[1], xc1 = pc_[1];
            DOT4(aA, pfG2, xa0); DOT4(aB, gb, xb0); DOT4(aC, gc, xc0);
            LDW4(ga, UG2, kp16, 2); LDW4(gb, UGT2, kp16, 2); LDW4(gc, RG2, kp16, 2);
            const uint4 xa2 = pa_[2], xb2 = pb_[2], xc2 = pc_[2];
            DOT4(aA, ha, xa1); DOT4(aB, hb, xb1); DOT4(aC, hc, xc1);
            LDW4(ha, UG2, kp16, 3); LDW4(hb, UGT2, kp16, 3); LDW4(hc, RG2, kp16, 3);
            const uint4 xa3 = pa_[3], xb3 = pb_[3], xc3 = pc_[3];
            DOT4(aA, ga, xa2); DOT4(aB, gb, xb2); DOT4(aC, gc, xc2);
            LDW4(pfNS1, NS1, kp24, 0);           // covers B6..B7 region
            DOT4(aA, ha, xa3); DOT4(aB, hb, xb3); DOT4(aC, hc, xc3);
            *(float4*)(s_part + (w << 8) + cl4)          = aA;
            *(float4*)(s_part + 2048 + (w << 8) + cl4)   = aB;
            *(float4*)(s_part + 4096 + (w << 8) + cl4)   = aC;
        }
        barx();                                                // B6
        {
            const int s = tid >> 8;
            float v = b2sel;
            const float* pb = s_part + (s ? 2048 : 0) + c;
            #pragma unroll
            for (int i = 0; i < 8; ++i) v += pb[i << 8];
            v = fast_sigmoid(v);
            if (s) s_ut[c] = v; else r_u = v;
            if (tid < 256) {
                float v2 = rgb2;
                const float* pb2 = s_part + 4096 + c;
                #pragma unroll
                for (int i = 0; i < 8; ++i) v2 += pb2[i << 8];
                r_r = fast_sigmoid(v2);
                const unsigned int pk = packpair(r_ydec * r_r);
                if (!(lane & 1)) s_ns_h[c >> 1] = pk;
            }
        }
        barx();                                                // B7

        // ---- ns1 (K=384, 6 chunks, src s_ns_h) ----
        {
            const uint4* sn = (const uint4*)(s_ns_h + kp24);
            float4 aA = make_float4(0.f,0.f,0.f,0.f);
            uint4 nA[4], nB[4];
            const uint4 xq0 = sn[0];
            LDW4(nA, NS1, kp24, 1);  const uint4 xq1 = sn[1];
            DOT4(aA, pfNS1, xq0);
            LDW4(nB, NS1, kp24, 2);  const uint4 xq2 = sn[2];
            DOT4(aA, nA, xq1);
            LDW4(nA, NS1, kp24, 3);  const uint4 xq3 = sn[3];
            DOT4(aA, nB, xq2);
            LDW4(nB, NS1, kp24, 4);  const uint4 xq4 = sn[4];
            DOT4(aA, nA, xq3);
            LDW4(nA, NS1, kp24, 5);  const uint4 xq5 = sn[5];
            DOT4(aA, nB, xq4);
            LDW4(pfNS2, NS2, kp16, 0);           // covers B8..B9 region
            DOT4(aA, nA, xq5);
            *(float4*)(s_part + (w << 8) + cl4) = aA;
        }
        barx();                                                // B8
        if (tid < 256) {
            float v = nsb1;
            #pragma unroll
            for (int i = 0; i < 8; ++i) v += s_part[(i << 8) + c];
            v = fast_tanh(v);
            const unsigned int pk = packpair(v);
            if (!(lane & 1)) s_a_h[c >> 1] = pk;
        }
        barx();                                                // B9

        // ---- ns2 (K=256, 4 chunks, src s_a_h) ----
        {
            const uint4* sa = (const uint4*)(s_a_h + kp16);
            float4 aA = make_float4(0.f,0.f,0.f,0.f);
            uint4 nA[4], nB[4];
            const uint4 xq0 = sa[0];
            LDW4(nA, NS2, kp16, 1);  const uint4 xq1 = sa[1];
            DOT4(aA, pfNS2, xq0);
            LDW4(nB, NS2, kp16, 2);  const uint4 xq2 = sa[2];
            DOT4(aA, nA, xq1);
            LDW4(nA, NS2, kp16, 3);  const uint4 xq3 = sa[3];
            DOT4(aA, nB, xq2);
            LDW4(pfDK, DK1, kp16, 0);            // covers B10..B11 + next stage
            DOT4(aA, nA, xq3);
            *(float4*)(s_part + (w << 8) + cl4) = aA;
        }
        barx();                                                // B10
        if (tid < 256) {
            float nsv = nsb2;
            #pragma unroll
            for (int i = 0; i < 8; ++i) nsv += s_part[(i << 8) + c];
            const float u = r_u, ut = s_ut[c];
            const float ny  = (1.f - u)  * nsv + u  * r_ydec;
            const float nyt = (1.f - ut) * nsv + ut * r_yt;
            r_y  = maskv ? ny  : r_ydec;
            r_yt = maskv ? nyt : r_yt;
            const unsigned int pk = packpair(r_y);
            if (!(lane & 1)) s_y_h[c >> 1] = pk;
        }
        barx();                                                // B11
    }

    if (tid < 256)
        out[(size_t)traj * 256 + c] = r_y;
}

extern "C" void kernel_launch(void* const* d_in, const int* in_sizes, int n_in,
                              void* d_out, int out_size, void* d_ws, size_t ws_size,
                              hipStream_t stream) {
    const float* data   = (const float*)d_in[0];
    const float* ts     = (const float*)d_in[1];
    const float* ug_w1  = (const float*)d_in[2];
    const float* ug_b1  = (const float*)d_in[3];
    const float* ug_w2  = (const float*)d_in[4];
    const float* ug_b2  = (const float*)d_in[5];
    const float* ugt_w1 = (const float*)d_in[6];
    const float* ugt_b1 = (const float*)d_in[7];
    const float* ugt_w2 = (const float*)d_in[8];
    const float* ugt_b2 = (const float*)d_in[9];
    const float* rg_w1  = (const float*)d_in[10];
    const float* rg_b1  = (const float*)d_in[11];
    const float* rg_w2  = (const float*)d_in[12];
    const float* rg_b2  = (const float*)d_in[13];
    // d_in[14..17] = rgt_* : unused by the reference
    const float* ns_w1  = (const float*)d_in[18];
    const float* ns_b1  = (const float*)d_in[19];
    const float* ns_w2  = (const float*)d_in[20];
    const float* ns_b2  = (const float*)d_in[21];
    const float* dk_w1  = (const float*)d_in[22];
    const float* dk_b1  = (const float*)d_in[23];
    const float* dk_w2  = (const float*)d_in[24];
    const float* dk_b2  = (const float*)d_in[25];
    const float* dec_w  = (const float*)d_in[26];
    const float* dec_b  = (const float*)d_in[27];

    unsigned int* wsu = (unsigned int*)d_ws;

    convert_w<<<WU_TOT / 256, 256, 0, stream>>>(ug_w1, ug_w2, ugt_w1, ugt_w2,
                                                rg_w1, rg_w2, ns_w1, ns_w2,
                                                dk_w1, dec_w, wsu);

    rnn_decay_kernel3<<<NTRAJ, 512, 0, stream>>>(
        data, ts, ug_b1, ug_b2, ugt_b1, ugt_b2, rg_b1, rg_b2, ns_b1, ns_b2,
        dk_b1, dk_w2, dk_b2, dec_b, wsu, (float*)d_out);
}

// Round 4
// 8042.471 us; speedup vs baseline: 3.4450x; 3.4450x over previous
//
#include <hip/hip_runtime.h>
#include <hip/hip_fp16.h>

#define NTRAJ   256
#define NTP     512
#define NSTEPS  511
#define LATENT  256
#define INPUT   128
#define DEC_OUT 128

#define OUT_VOL ((size_t)NTRAJ * LATENT)                              // 65536
#define OUT_DTS (OUT_VOL + (size_t)NTRAJ * NSTEPS * DEC_OUT)          // 16809984

// Pair-interleaved fp16 weight workspace (offsets in uint32 = half2 units).
// Layout per matrix [K][C]: ws[kp*C + c] = half2(W[2kp][c], W[2kp+1][c]).
#define WU_UG1  0
#define WU_UG2  49152
#define WU_UGT1 81920
#define WU_UGT2 131072
#define WU_RG1  163840
#define WU_RG2  212992
#define WU_NS1  245760
#define WU_NS2  294912
#define WU_DK1  327680
#define WU_DEC  360448
#define WU_TOT  376832

typedef _Float16 h2_t __attribute__((ext_vector_type(2)));
union U32H2 { unsigned int u; h2_t h; };

__device__ __forceinline__ float dot2f(unsigned int wu, unsigned int xu, float acc) {
#if defined(__has_builtin) && __has_builtin(__builtin_amdgcn_fdot2)
    U32H2 a, b; a.u = wu; b.u = xu;
    return __builtin_amdgcn_fdot2(a.h, b.h, acc, false);
#else
    U32H2 a, b; a.u = wu; b.u = xu;
    return acc + (float)a.h.x * (float)b.h.x + (float)a.h.y * (float)b.h.y;
#endif
}

__device__ __forceinline__ float wred(float v) {
    #pragma unroll
    for (int off = 32; off; off >>= 1) v += __shfl_down(v, off, 64);
    return v;
}
__device__ __forceinline__ float fast_sigmoid(float x) { return 1.0f / (1.0f + __expf(-x)); }
__device__ __forceinline__ float fast_tanh(float x) {
    float e = __expf(2.0f * x);
    return 1.0f - 2.0f / (e + 1.0f);
}
// Pack (v_even, v_odd) from adjacent lanes into one half2; only even lanes
// hold the correct result and write. Must be called by full waves.
__device__ __forceinline__ unsigned int packpair(float v) {
    float vn = __shfl_xor(v, 1, 64);
    U32H2 r; r.h.x = (_Float16)v; r.h.y = (_Float16)vn;
    return r.u;
}
// Pack two in-lane floats into one half2 word (no shuffle needed).
__device__ __forceinline__ unsigned int pk2(float a, float b) {
    U32H2 r; r.h.x = (_Float16)a; r.h.y = (_Float16)b; return r.u;
}
// Butterfly-add a float4 across lanes at xor-distance m.
__device__ __forceinline__ float4 bfly4(float4 v, int m) {
    v.x += __shfl_xor(v.x, m, 64);
    v.y += __shfl_xor(v.y, m, 64);
    v.z += __shfl_xor(v.z, m, 64);
    v.w += __shfl_xor(v.w, m, 64);
    return v;
}

// ---- weight prep: fp32 -> k-pair-interleaved half2 ----
extern "C" __global__ void __launch_bounds__(256)
convert_w(const float* __restrict__ ug_w1, const float* __restrict__ ug_w2,
          const float* __restrict__ ugt_w1, const float* __restrict__ ugt_w2,
          const float* __restrict__ rg_w1, const float* __restrict__ rg_w2,
          const float* __restrict__ ns_w1, const float* __restrict__ ns_w2,
          const float* __restrict__ dk_w1, const float* __restrict__ dec_w,
          unsigned int* __restrict__ ws)
{
    const int i = blockIdx.x * 256 + threadIdx.x;
    const float* s; int o; int cbits;
    if      (i < WU_UG2)  { s = ug_w1;  o = i;           cbits = 8; }
    else if (i < WU_UGT1) { s = ug_w2;  o = i - WU_UG2;  cbits = 8; }
    else if (i < WU_UGT2) { s = ugt_w1; o = i - WU_UGT1; cbits = 8; }
    else if (i < WU_RG1)  { s = ugt_w2; o = i - WU_UGT2; cbits = 8; }
    else if (i < WU_RG2)  { s = rg_w1;  o = i - WU_RG1;  cbits = 8; }
    else if (i < WU_NS1)  { s = rg_w2;  o = i - WU_RG2;  cbits = 8; }
    else if (i < WU_NS2)  { s = ns_w1;  o = i - WU_NS1;  cbits = 8; }
    else if (i < WU_DK1)  { s = ns_w2;  o = i - WU_NS2;  cbits = 8; }
    else if (i < WU_DEC)  { s = dk_w1;  o = i - WU_DK1;  cbits = 8; }
    else                  { s = dec_w;  o = i - WU_DEC;  cbits = 7; }
    const int C  = 1 << cbits;
    const int kp = o >> cbits;
    const int c  = o & (C - 1);
    const float v0 = s[(2 * kp) * C + c];
    const float v1 = s[(2 * kp + 1) * C + c];
    const unsigned int h0 = __half_as_ushort(__float2half(v0));
    const unsigned int h1 = __half_as_ushort(__float2half(v1));
    ws[i] = h0 | (h1 << 16);
}

// Macro hygiene: no parameter named x/y/z/w (body does member access).
// acc.{x,y,z,w} are 4 adjacent output columns sharing one x half2.
#define DOT1(acc, wv, xv) { \
    acc.x = dot2f((wv).x, (xv), acc.x); acc.y = dot2f((wv).y, (xv), acc.y); \
    acc.z = dot2f((wv).z, (xv), acc.z); acc.w = dot2f((wv).w, (xv), acc.w); }

extern "C" __global__ void __launch_bounds__(512, 2)
rnn_decay_kernel4(const float* __restrict__ data, const float* __restrict__ ts,
                  const float* __restrict__ ug_b1, const float* __restrict__ ug_b2,
                  const float* __restrict__ ugt_b1, const float* __restrict__ ugt_b2,
                  const float* __restrict__ rg_b1, const float* __restrict__ rg_b2,
                  const float* __restrict__ ns_b1, const float* __restrict__ ns_b2,
                  const float* __restrict__ dk_b1, const float* __restrict__ dk_w2,
                  const float* __restrict__ dk_b2, const float* __restrict__ dec_b,
                  const unsigned int* __restrict__ wsu, float* __restrict__ out)
{
    // Column-split decomposition: wave w owns output cols [32w,32w+32);
    // lane owns 4 adjacent cols; 8 kp-slices per wave, reduced via shfl_xor.
    // No s_part, no cross-wave GEMV reduce, 1 barrier per stage (6/step).
    __shared__ __align__(16) unsigned int s_in_h[192];  // [ydec(128)|xh(64)] half2
    __shared__ __align__(16) unsigned int s_ns_h[192];  // [y*r (128)|xh(64)] half2
    __shared__ __align__(16) unsigned int s_y_h[128];   // y half2 (dk1 src)
    __shared__ __align__(16) unsigned int s_a_h[128];   // h / ns-h half2
    __shared__ __align__(16) unsigned int s_b_h[128];   // ht half2
    __shared__ __align__(16) unsigned int s_c_h[128];   // hr half2
    __shared__ __align__(16) unsigned int s_v_h[128];   // vol half2
    __shared__ float s_red[12];                         // [0..3] mask, [4..11] dk

    const int tid  = threadIdx.x;
    const int w    = tid >> 6;
    const int lane = tid & 63;
    const int c    = tid & 255;
    const int sl   = lane >> 3;                 // kp slice 0..7
    const int g    = lane & 7;                  // col group 0..7
    const int c0   = (w << 5) + (g << 2);       // first of 4 owned cols (0..252)
    const int h2b  = c0 >> 1;                   // half2-unit base for packs
    const int sld  = lane >> 2;                 // dec: kp slice 0..15
    const int c0d  = (w << 4) + ((lane & 3) << 2);  // dec: first of 4 cols (0..124)
    const int traj = blockIdx.x;

    const unsigned int* UG1  = wsu + WU_UG1;  const unsigned int* UG2  = wsu + WU_UG2;
    const unsigned int* UGT1 = wsu + WU_UGT1; const unsigned int* UGT2 = wsu + WU_UGT2;
    const unsigned int* RG1  = wsu + WU_RG1;  const unsigned int* RG2  = wsu + WU_RG2;
    const unsigned int* NS1  = wsu + WU_NS1;  const unsigned int* NS2  = wsu + WU_NS2;
    const unsigned int* DK1  = wsu + WU_DK1;  const unsigned int* DECW = wsu + WU_DEC;

    const float* dbase = data + (size_t)traj * NTP * (2 * INPUT);
    const float* tbase = ts + (size_t)traj * NTP;
    float* vol_out = out + OUT_VOL + (size_t)traj * NSTEPS * DEC_OUT;
    float* dts_out = out + OUT_DTS + (size_t)traj * NSTEPS;

    if (tid < 256)
        for (int t0 = c; t0 < NSTEPS; t0 += 256)
            dts_out[t0] = tbase[t0 + 1] - tbase[t0];

    // Per-lane bias/vector constants for the 4 owned columns (loop-invariant).
    const float4 ugb1v  = *(const float4*)(ug_b1  + c0);
    const float4 ugtb1v = *(const float4*)(ugt_b1 + c0);
    const float4 rgb1v  = *(const float4*)(rg_b1  + c0);
    const float4 nsb1v  = *(const float4*)(ns_b1  + c0);
    const float4 ugb2v  = *(const float4*)(ug_b2  + c0);
    const float4 ugtb2v = *(const float4*)(ugt_b2 + c0);
    const float4 rgb2v  = *(const float4*)(rg_b2  + c0);
    const float4 nsb2v  = *(const float4*)(ns_b2  + c0);
    const float4 dkb1v  = *(const float4*)(dk_b1  + c0);
    const float4 dkw2v  = *(const float4*)(dk_w2  + c0);
    const float4 decbv  = *(const float4*)(dec_b  + c0d);
    const float  dkb2s  = dk_b2[0];

    float4 y4  = make_float4(0.f, 0.f, 0.f, 0.f);   // GRU state: owned cols
    float4 yt4 = y4;

    for (int t = -1; t < NSTEPS; ++t) {
        const bool first = (t < 0);

        // ================= phase X: x-stage + mask + dk1 dot =================
        float dt_t = 0.f;
        if (!first) dt_t = tbase[t + 1] - tbase[t];
        float xval = 0.f;
        if (tid < 256)
            xval = first ? dbase[c] : dbase[(size_t)(t + 1) * 256 + c];

        if (!first) {
            float4 aD = make_float4(0.f, 0.f, 0.f, 0.f);
            #pragma unroll 4
            for (int i = 0; i < 16; ++i) {
                const int kp = sl + (i << 3);
                const unsigned int xv = s_y_h[kp];
                const uint4 wv = *(const uint4*)(DK1 + (size_t)kp * 256 + c0);
                DOT1(aD, wv, xv);
            }
            aD = bfly4(aD, 8); aD = bfly4(aD, 16); aD = bfly4(aD, 32);
            float sdk = fmaxf(aD.x + dkb1v.x, 0.f) * dkw2v.x
                      + fmaxf(aD.y + dkb1v.y, 0.f) * dkw2v.y
                      + fmaxf(aD.z + dkb1v.z, 0.f) * dkw2v.z
                      + fmaxf(aD.w + dkb1v.w, 0.f) * dkw2v.w;
            sdk += __shfl_xor(sdk, 1, 64);
            sdk += __shfl_xor(sdk, 2, 64);
            sdk += __shfl_xor(sdk, 4, 64);
            if (lane == 0) s_red[4 + w] = sdk;
        }
        if (tid < 256) {
            float mv = (c >= 128) ? xval : 0.f;
            mv = wred(mv);
            if (lane == 0) s_red[w] = mv;               // w in 0..3 here
            if (c < 128) {
                const unsigned int px = packpair(xval);
                if (!(lane & 1)) { s_in_h[128 + (c >> 1)] = px; s_ns_h[128 + (c >> 1)] = px; }
            }
            if (first && !(lane & 1)) s_in_h[c >> 1] = 0u;   // ydec = 0
        }
        __syncthreads();                                               // A

        // ================= phase Y: decay scalar + ydec/vol pack =============
        const bool maskv = (s_red[0] + s_red[1] + s_red[2] + s_red[3]) > 0.f;
        float4 ydec4 = make_float4(0.f, 0.f, 0.f, 0.f);
        if (!first) {
            const float decay = fmaxf(s_red[4] + s_red[5] + s_red[6] + s_red[7]
                                    + s_red[8] + s_red[9] + s_red[10] + s_red[11]
                                    + dkb2s, 0.f);
            const float ef = __expf(-decay * dt_t);
            const float eh = __expf(-0.5f * decay * dt_t);
            float4 vol4;
            ydec4.x = yt4.x + (y4.x - yt4.x) * ef;
            ydec4.y = yt4.y + (y4.y - yt4.y) * ef;
            ydec4.z = yt4.z + (y4.z - yt4.z) * ef;
            ydec4.w = yt4.w + (y4.w - yt4.w) * ef;
            vol4.x = 0.5f * (y4.x + yt4.x + (y4.x - yt4.x) * eh);
            vol4.y = 0.5f * (y4.y + yt4.y + (y4.y - yt4.y) * eh);
            vol4.z = 0.5f * (y4.z + yt4.z + (y4.z - yt4.z) * eh);
            vol4.w = 0.5f * (y4.w + yt4.w + (y4.w - yt4.w) * eh);
            if (!sl) {
                uint2 pd; pd.x = pk2(ydec4.x, ydec4.y); pd.y = pk2(ydec4.z, ydec4.w);
                uint2 pv; pv.x = pk2(vol4.x, vol4.y);   pv.y = pk2(vol4.z, vol4.w);
                *(uint2*)(s_in_h + h2b) = pd;
                *(uint2*)(s_v_h + h2b)  = pv;
            }
        }
        __syncthreads();                                               // B

        // ================= phase G1: dec + ug1/ugt1/rg1 ======================
        if (!first) {
            float4 aE = make_float4(0.f, 0.f, 0.f, 0.f);
            #pragma unroll 4
            for (int i = 0; i < 8; ++i) {
                const int kp = sld + (i << 4);
                const unsigned int xv = s_v_h[kp];
                const uint4 wv = *(const uint4*)(DECW + (size_t)kp * 128 + c0d);
                DOT1(aE, wv, xv);
            }
            aE = bfly4(aE, 4); aE = bfly4(aE, 8); aE = bfly4(aE, 16); aE = bfly4(aE, 32);
            if (sld == 0) {
                float4 o;
                o.x = aE.x + decbv.x; o.y = aE.y + decbv.y;
                o.z = aE.z + decbv.z; o.w = aE.w + decbv.w;
                *(float4*)(vol_out + (size_t)t * DEC_OUT + c0d) = o;
            }
        }
        {
            float4 aA = make_float4(0.f, 0.f, 0.f, 0.f), aB = aA, aC = aA;
            #pragma unroll 4
            for (int i = 0; i < 24; ++i) {
                const int kp = sl + (i << 3);
                const unsigned int xv = s_in_h[kp];
                const uint4 wa = *(const uint4*)(UG1  + (size_t)kp * 256 + c0);
                const uint4 wb = *(const uint4*)(UGT1 + (size_t)kp * 256 + c0);
                const uint4 wc = *(const uint4*)(RG1  + (size_t)kp * 256 + c0);
                DOT1(aA, wa, xv); DOT1(aB, wb, xv); DOT1(aC, wc, xv);
            }
            aA = bfly4(aA, 8); aA = bfly4(aA, 16); aA = bfly4(aA, 32);
            aB = bfly4(aB, 8); aB = bfly4(aB, 16); aB = bfly4(aB, 32);
            aC = bfly4(aC, 8); aC = bfly4(aC, 16); aC = bfly4(aC, 32);
            if (!sl) {
                uint2 pa, pb, pc;
                pa.x = pk2(fast_tanh(aA.x + ugb1v.x),  fast_tanh(aA.y + ugb1v.y));
                pa.y = pk2(fast_tanh(aA.z + ugb1v.z),  fast_tanh(aA.w + ugb1v.w));
                pb.x = pk2(fast_tanh(aB.x + ugtb1v.x), fast_tanh(aB.y + ugtb1v.y));
                pb.y = pk2(fast_tanh(aB.z + ugtb1v.z), fast_tanh(aB.w + ugtb1v.w));
                pc.x = pk2(fast_tanh(aC.x + rgb1v.x),  fast_tanh(aC.y + rgb1v.y));
                pc.y = pk2(fast_tanh(aC.z + rgb1v.z),  fast_tanh(aC.w + rgb1v.w));
                *(uint2*)(s_a_h + h2b) = pa;
                *(uint2*)(s_b_h + h2b) = pb;
                *(uint2*)(s_c_h + h2b) = pc;
            }
        }
        __syncthreads();                                               // C

        // ================= phase G2: ug2/ugt2/rg2 → u, ut, r =================
        float4 u4, ut4;
        {
            float4 aA = make_float4(0.f, 0.f, 0.f, 0.f), aB = aA, aC = aA;
            #pragma unroll 4
            for (int i = 0; i < 16; ++i) {
                const int kp = sl + (i << 3);
                const unsigned int xa = s_a_h[kp];
                const unsigned int xb = s_b_h[kp];
                const unsigned int xc = s_c_h[kp];
                const uint4 wa = *(const uint4*)(UG2  + (size_t)kp * 256 + c0);
                const uint4 wb = *(const uint4*)(UGT2 + (size_t)kp * 256 + c0);
                const uint4 wc = *(const uint4*)(RG2  + (size_t)kp * 256 + c0);
                DOT1(aA, wa, xa); DOT1(aB, wb, xb); DOT1(aC, wc, xc);
            }
            aA = bfly4(aA, 8); aA = bfly4(aA, 16); aA = bfly4(aA, 32);
            aB = bfly4(aB, 8); aB = bfly4(aB, 16); aB = bfly4(aB, 32);
            aC = bfly4(aC, 8); aC = bfly4(aC, 16); aC = bfly4(aC, 32);
            u4.x  = fast_sigmoid(aA.x + ugb2v.x);  u4.y  = fast_sigmoid(aA.y + ugb2v.y);
            u4.z  = fast_sigmoid(aA.z + ugb2v.z);  u4.w  = fast_sigmoid(aA.w + ugb2v.w);
            ut4.x = fast_sigmoid(aB.x + ugtb2v.x); ut4.y = fast_sigmoid(aB.y + ugtb2v.y);
            ut4.z = fast_sigmoid(aB.z + ugtb2v.z); ut4.w = fast_sigmoid(aB.w + ugtb2v.w);
            const float rx = fast_sigmoid(aC.x + rgb2v.x);
            const float ry = fast_sigmoid(aC.y + rgb2v.y);
            const float rz = fast_sigmoid(aC.z + rgb2v.z);
            const float rw = fast_sigmoid(aC.w + rgb2v.w);
            if (!sl) {
                uint2 pn;
                pn.x = pk2(ydec4.x * rx, ydec4.y * ry);
                pn.y = pk2(ydec4.z * rz, ydec4.w * rw);
                *(uint2*)(s_ns_h + h2b) = pn;      // first step: ydec=0 → 0 ✓
            }
        }
        __syncthreads();                                               // D

        // ================= phase N1: ns1 =====================================
        {
            float4 aA = make_float4(0.f, 0.f, 0.f, 0.f);
            #pragma unroll 4
            for (int i = 0; i < 24; ++i) {
                const int kp = sl + (i << 3);
                const unsigned int xv = s_ns_h[kp];
                const uint4 wa = *(const uint4*)(NS1 + (size_t)kp * 256 + c0);
                DOT1(aA, wa, xv);
            }
            aA = bfly4(aA, 8); aA = bfly4(aA, 16); aA = bfly4(aA, 32);
            if (!sl) {
                uint2 ph;
                ph.x = pk2(fast_tanh(aA.x + nsb1v.x), fast_tanh(aA.y + nsb1v.y));
                ph.y = pk2(fast_tanh(aA.z + nsb1v.z), fast_tanh(aA.w + nsb1v.w));
                *(uint2*)(s_a_h + h2b) = ph;       // reuse s_a_h (G2 done)
            }
        }
        __syncthreads();                                               // E

        // ================= phase N2: ns2 + state update ======================
        {
            float4 aA = make_float4(0.f, 0.f, 0.f, 0.f);
            #pragma unroll 4
            for (int i = 0; i < 16; ++i) {
                const int kp = sl + (i << 3);
                const unsigned int xv = s_a_h[kp];
                const uint4 wa = *(const uint4*)(NS2 + (size_t)kp * 256 + c0);
                DOT1(aA, wa, xv);
            }
            aA = bfly4(aA, 8); aA = bfly4(aA, 16); aA = bfly4(aA, 32);
            const float nx = aA.x + nsb2v.x, ny_ = aA.y + nsb2v.y;
            const float nz = aA.z + nsb2v.z, nw = aA.w + nsb2v.w;
            const float yx = (1.f - u4.x) * nx  + u4.x * ydec4.x;
            const float yy = (1.f - u4.y) * ny_ + u4.y * ydec4.y;
            const float yz = (1.f - u4.z) * nz  + u4.z * ydec4.z;
            const float yw = (1.f - u4.w) * nw  + u4.w * ydec4.w;
            const float tx = (1.f - ut4.x) * nx  + ut4.x * yt4.x;
            const float ty = (1.f - ut4.y) * ny_ + ut4.y * yt4.y;
            const float tz = (1.f - ut4.z) * nz  + ut4.z * yt4.z;
            const float tw = (1.f - ut4.w) * nw  + ut4.w * yt4.w;
            y4.x  = maskv ? yx : ydec4.x;  y4.y  = maskv ? yy : ydec4.y;
            y4.z  = maskv ? yz : ydec4.z;  y4.w  = maskv ? yw : ydec4.w;
            yt4.x = maskv ? tx : yt4.x;    yt4.y = maskv ? ty : yt4.y;
            yt4.z = maskv ? tz : yt4.z;    yt4.w = maskv ? tw : yt4.w;
            if (!sl) {
                uint2 py;
                py.x = pk2(y4.x, y4.y); py.y = pk2(y4.z, y4.w);
                *(uint2*)(s_y_h + h2b) = py;
            }
        }
        __syncthreads();                                               // F
    }

    if (!sl)
        *(float4*)(out + (size_t)traj * 256 + c0) = y4;
}

extern "C" void kernel_launch(void* const* d_in, const int* in_sizes, int n_in,
                              void* d_out, int out_size, void* d_ws, size_t ws_size,
                              hipStream_t stream) {
    const float* data   = (const float*)d_in[0];
    const float* ts     = (const float*)d_in[1];
    const float* ug_w1  = (const float*)d_in[2];
    const float* ug_b1  = (const float*)d_in[3];
    const float* ug_w2  = (const float*)d_in[4];
    const float* ug_b2  = (const float*)d_in[5];
    const float* ugt_w1 = (const float*)d_in[6];
    const float* ugt_b1 = (const float*)d_in[7];
    const float* ugt_w2 = (const float*)d_in[8];
    const float* ugt_b2 = (const float*)d_in[9];
    const float* rg_w1  = (const float*)d_in[10];
    const float* rg_b1  = (const float*)d_in[11];
    const float* rg_w2  = (const float*)d_in[12];
    const float* rg_b2  = (const float*)d_in[13];
    // d_in[14..17] = rgt_* : unused by the reference
    const float* ns_w1  = (const float*)d_in[18];
    const float* ns_b1  = (const float*)d_in[19];
    const float* ns_w2  = (const float*)d_in[20];
    const float* ns_b2  = (const float*)d_in[21];
    const float* dk_w1  = (const float*)d_in[22];
    const float* dk_b1  = (const float*)d_in[23];
    const float* dk_w2  = (const float*)d_in[24];
    const float* dk_b2  = (const float*)d_in[25];
    const float* dec_w  = (const float*)d_in[26];
    const float* dec_b  = (const float*)d_in[27];

    unsigned int* wsu = (unsigned int*)d_ws;

    convert_w<<<WU_TOT / 256, 256, 0, stream>>>(ug_w1, ug_w2, ugt_w1, ugt_w2,
                                                rg_w1, rg_w2, ns_w1, ns_w2,
                                                dk_w1, dec_w, wsu);

    rnn_decay_kernel4<<<NTRAJ, 512, 0, stream>>>(
        data, ts, ug_b1, ug_b2, ugt_b1, ugt_b2, rg_b1, rg_b2, ns_b1, ns_b2,
        dk_b1, dk_w2, dk_b2, dec_b, wsu, (float*)d_out);
}